// Round 1
// baseline (76.026 us; speedup 1.0000x reference)
//
#include <hip/hip_runtime.h>
#include <hip/hip_bf16.h>
#include <math.h>

// Problem shape (fixed by reference setup_inputs): B=8, L=4096, D=512
#define B_ 8
#define L_ 4096
#define D_ 512

// ws layout (bytes):
//   0      : int  nonid flag
//   64     : int  ksum[B_]
//   128    : u8   hard[B_*L_]            (32768 B)
//   33024  : int  seg_starts[B_*L_]      (131072 B)
//   164096 : f32  M[D_*D_]               (1 MiB, only for general path)

__device__ __forceinline__ float wave_reduce_add(float v) {
#pragma unroll
    for (int o = 32; o > 0; o >>= 1) v += __shfl_xor(v, o, 64);
    return v;
}

__global__ void k_check_identity(const float* __restrict__ q_w,
                                 const float* __restrict__ k_w,
                                 int* __restrict__ nonid) {
    int stride = gridDim.x * blockDim.x;
    bool bad = false;
    for (int i = blockIdx.x * blockDim.x + threadIdx.x; i < D_ * D_; i += stride) {
        int r = i >> 9, c = i & (D_ - 1);
        float e = (r == c) ? 1.0f : 0.0f;
        if (q_w[i] != e || k_w[i] != e) bad = true;
    }
    if (bad) atomicOr(nonid, 1);
}

// M = q_w^T @ k_w  (only computed when weights are not identity)
__global__ void k_compute_M(const float* __restrict__ q_w,
                            const float* __restrict__ k_w,
                            const int* __restrict__ nonid,
                            float* __restrict__ M) {
    if (*nonid == 0) return;
    int i = blockIdx.x;  // row of M
    for (int j = threadIdx.x; j < D_; j += blockDim.x) {
        float acc = 0.0f;
        for (int d = 0; d < D_; ++d) acc += q_w[d * D_ + i] * k_w[d * D_ + j];
        M[i * D_ + j] = acc;
    }
}

// One wave per (b,l) position: compute hard boundary decision.
__global__ __launch_bounds__(256) void k_boundary(const float* __restrict__ hidden,
                                                  const float* __restrict__ noise,
                                                  const float* __restrict__ M,
                                                  const int* __restrict__ nonid,
                                                  unsigned char* __restrict__ hard) {
    __shared__ float lds[4 * D_];
    int wid = threadIdx.x >> 6;
    int lane = threadIdx.x & 63;
    int pos = blockIdx.x * 4 + wid;  // pos in [0, B_*L_)
    int l = pos & (L_ - 1);

    unsigned char h;
    if (l == 0) {
        h = 1;  // padded first position: probs=1 -> logits=+inf -> hard=1
    } else {
        const float* rowL = hidden + ((size_t)pos - 1) * D_;
        const float* rowR = hidden + (size_t)pos * D_;
        float cosv;
        if (*nonid == 0) {
            // identity weights: cos = dot(h_l, h_r) / (||h_l|| * ||h_r||)
            float dot = 0.f, ssl = 0.f, ssr = 0.f;
#pragma unroll
            for (int c = 0; c < 2; ++c) {
                int idx = lane * 4 + c * 256;
                float4 a = *(const float4*)(rowL + idx);
                float4 bb = *(const float4*)(rowR + idx);
                dot += a.x * bb.x + a.y * bb.y + a.z * bb.z + a.w * bb.w;
                ssl += a.x * a.x + a.y * a.y + a.z * a.z + a.w * a.w;
                ssr += bb.x * bb.x + bb.y * bb.y + bb.z * bb.z + bb.w * bb.w;
            }
            dot = wave_reduce_add(dot);
            ssl = wave_reduce_add(ssl);
            ssr = wave_reduce_add(ssr);
            float nl = fmaxf(sqrtf(ssl), 1e-12f);
            float nr = fmaxf(sqrtf(ssr), 1e-12f);
            cosv = dot / (nl * nr);
        } else {
            // general: cos = n_l^T M n_r
            float ssl = 0.f, ssr = 0.f;
#pragma unroll
            for (int c = 0; c < 2; ++c) {
                int idx = lane * 4 + c * 256;
                float4 a = *(const float4*)(rowL + idx);
                float4 bb = *(const float4*)(rowR + idx);
                ssl += a.x * a.x + a.y * a.y + a.z * a.z + a.w * a.w;
                ssr += bb.x * bb.x + bb.y * bb.y + bb.z * bb.z + bb.w * bb.w;
            }
            ssl = wave_reduce_add(ssl);
            ssr = wave_reduce_add(ssr);
            float nl = fmaxf(sqrtf(ssl), 1e-12f);
            float nr = fmaxf(sqrtf(ssr), 1e-12f);
            float* nr_lds = lds + wid * D_;  // per-wave region, no block barrier needed
#pragma unroll
            for (int c = 0; c < 2; ++c) {
                int idx = lane * 4 + c * 256;
                float4 bb = *(const float4*)(rowR + idx);
                nr_lds[idx + 0] = bb.x / nr;
                nr_lds[idx + 1] = bb.y / nr;
                nr_lds[idx + 2] = bb.z / nr;
                nr_lds[idx + 3] = bb.w / nr;
            }
            float acc = 0.f;
#pragma unroll
            for (int r8 = 0; r8 < 8; ++r8) {
                int i = lane + 64 * r8;
                float wi = 0.f;
                for (int j = 0; j < D_; ++j) wi += M[i * D_ + j] * nr_lds[j];
                acc += (rowL[i] / nl) * wi;
            }
            cosv = wave_reduce_add(acc);
        }
        float p = fminf(fmaxf(0.5f * (1.0f - cosv), 0.0f), 1.0f);
        float u = noise[pos];
        // match reference op order; IEEE inf handles p==0 / p==1 correctly
        float x = (logf(p) - log1pf(-p)) + (logf(u) - log1pf(-u));
        float s = 1.0f / (1.0f + expf(-x));
        h = (s > 0.5f) ? (unsigned char)1 : (unsigned char)0;
    }
    if (lane == 0) hard[pos] = h;
}

// Per-batch-row inclusive scan of hard flags -> segment start positions + count.
__global__ __launch_bounds__(256) void k_scan(const unsigned char* __restrict__ hard,
                                              int* __restrict__ seg_starts,
                                              int* __restrict__ ksum) {
    int b = blockIdx.x;
    int tid = threadIdx.x;
    const unsigned char* hb = hard + b * L_;
    int base = tid * 16;
    int loc[16];
    int s = 0;
#pragma unroll
    for (int i = 0; i < 16; ++i) {
        loc[i] = hb[base + i];
        s += loc[i];
    }
    __shared__ int sdata[256];
    sdata[tid] = s;
    __syncthreads();
    for (int off = 1; off < 256; off <<= 1) {
        int v = (tid >= off) ? sdata[tid - off] : 0;
        __syncthreads();
        sdata[tid] += v;
        __syncthreads();
    }
    int excl = sdata[tid] - s;
    int run = excl;
#pragma unroll
    for (int i = 0; i < 16; ++i) {
        run += loc[i];
        if (loc[i]) seg_starts[b * L_ + run - 1] = base + i;
    }
    if (tid == 255) ksum[b] = sdata[255];
}

// One block per (segment slot j, batch b): mean-pool contiguous token range,
// or write zeros for empty slots. Output layout: pooled[j, b, d].
__global__ __launch_bounds__(128) void k_pool(const float* __restrict__ hidden,
                                              const int* __restrict__ seg_starts,
                                              const int* __restrict__ ksum,
                                              float* __restrict__ out) {
    int j = blockIdx.x, b = blockIdx.y;
    int S = ksum[b];
    int tid = threadIdx.x;
    float4 acc = make_float4(0.f, 0.f, 0.f, 0.f);
    if (j < S) {
        int start = seg_starts[b * L_ + j];
        int end = (j + 1 < S) ? seg_starts[b * L_ + j + 1] : L_;
        for (int t = start; t < end; ++t) {
            const float4* r = (const float4*)(hidden + ((size_t)b * L_ + t) * D_);
            float4 v = r[tid];
            acc.x += v.x;
            acc.y += v.y;
            acc.z += v.z;
            acc.w += v.w;
        }
        float len = (float)(end - start);
        acc.x /= len;
        acc.y /= len;
        acc.z /= len;
        acc.w /= len;
    }
    float4* o = (float4*)(out + ((size_t)j * B_ + b) * D_);
    o[tid] = acc;
}

__global__ void k_loss(const int* __restrict__ ksum, float* __restrict__ out_loss) {
    if (threadIdx.x == 0 && blockIdx.x == 0) {
        double n = (double)L_;
        double acc = 0.0;
        for (int b = 0; b < B_; ++b) {
            double k = (double)ksum[b];
            double lp = lgamma(n + 1.0) - lgamma(k + 1.0) - lgamma(n - k + 1.0) +
                        k * log(0.2) + (n - k) * log(0.8);
            acc += lp;
        }
        out_loss[0] = (float)(-(acc / (double)B_) / n);
    }
}

extern "C" void kernel_launch(void* const* d_in, const int* in_sizes, int n_in,
                              void* d_out, int out_size, void* d_ws, size_t ws_size,
                              hipStream_t stream) {
    const float* hidden = (const float*)d_in[0];
    const float* q_w = (const float*)d_in[1];
    const float* k_w = (const float*)d_in[2];
    const float* noise = (const float*)d_in[3];
    float* out = (float*)d_out;

    char* ws = (char*)d_ws;
    int* nonid = (int*)(ws + 0);
    int* ksum = (int*)(ws + 64);
    unsigned char* hard = (unsigned char*)(ws + 128);
    int* seg_starts = (int*)(ws + 33024);
    float* M = (float*)(ws + 164096);

    hipMemsetAsync(nonid, 0, 4, stream);
    k_check_identity<<<128, 256, 0, stream>>>(q_w, k_w, nonid);
    k_compute_M<<<D_, 256, 0, stream>>>(q_w, k_w, nonid, M);
    k_boundary<<<(B_ * L_) / 4, 256, 0, stream>>>(hidden, noise, M, nonid, hard);
    k_scan<<<B_, 256, 0, stream>>>(hard, seg_starts, ksum);
    k_pool<<<dim3(L_, B_), 128, 0, stream>>>(hidden, seg_starts, ksum, out);
    k_loss<<<1, 64, 0, stream>>>(ksum, out + (size_t)L_ * B_ * D_);
}

// Round 3
// 70.135 us; speedup vs baseline: 1.0840x; 1.0840x over previous
//
#include <hip/hip_runtime.h>
#include <hip/hip_bf16.h>
#include <math.h>

// Problem shape (fixed by reference setup_inputs): B=8, L=4096, D=512
#define B_ 8
#define L_ 4096
#define D_ 512
#define STRIP 8

typedef float f4 __attribute__((ext_vector_type(4)));

// ws layout (bytes):
//   0     : int nonid_arr[64]   (per-check-block flags)
//   512   : int ksum[B_]
//   1024  : u8  hard[B_*L_]     (32768 B; written 8 bytes at a time as u64)
//   34816 : int seg_starts[B_*L_]

__device__ __forceinline__ float wave_reduce_add(float v) {
#pragma unroll
    for (int o = 32; o > 0; o >>= 1) v += __shfl_xor(v, o, 64);
    return v;
}

// 64 blocks; block i writes nonid_arr[i] = (any mismatch vs identity in its slice)
__global__ __launch_bounds__(256) void k_check(const float* __restrict__ q_w,
                                               const float* __restrict__ k_w,
                                               int* __restrict__ nonid_arr) {
    int t = blockIdx.x * 256 + threadIdx.x;
    bool bad = false;
    for (int i = t; i < D_ * D_; i += 64 * 256) {
        int r = i >> 9, c = i & (D_ - 1);
        float e = (r == c) ? 1.0f : 0.0f;
        if (q_w[i] != e || k_w[i] != e) bad = true;
    }
    unsigned long long m = __ballot(bad);
    __shared__ unsigned long long s[4];
    if ((threadIdx.x & 63) == 0) s[threadIdx.x >> 6] = m;
    __syncthreads();
    if (threadIdx.x == 0)
        nonid_arr[blockIdx.x] = ((s[0] | s[1] | s[2] | s[3]) != 0ull) ? 1 : 0;
}

// One wave per strip of 8 consecutive positions; prev row carried in registers.
__global__ __launch_bounds__(256) void k_boundary(const float* __restrict__ hidden,
                                                  const float* __restrict__ noise,
                                                  const float* __restrict__ q_w,
                                                  const float* __restrict__ k_w,
                                                  const int* __restrict__ nonid_arr,
                                                  unsigned long long* __restrict__ hard64) {
    __shared__ float lds[4 * 2 * D_];  // per-wave nL / nR rows (general path only)
    int wid = threadIdx.x >> 6;
    int lane = threadIdx.x & 63;
    int wave = blockIdx.x * 4 + wid;        // in [0, B_ * L_/STRIP)
    int b = wave >> 9;                      // L_/STRIP = 512
    int t0 = (wave & 511) * STRIP;
    const float* base = hidden + (size_t)b * L_ * D_;
    bool nonid = __any(nonid_arr[lane] != 0);
    int i0 = lane * 4, i1 = lane * 4 + 256;

    // prev row = row (t0-1), clamped to 0 for the first strip
    int rp = (t0 > 0) ? (t0 - 1) : 0;
    f4 pa = *(const f4*)(base + (size_t)rp * D_ + i0);
    f4 pb = *(const f4*)(base + (size_t)rp * D_ + i1);
    float ssl = 0.0f;
    {
        float s = 0.0f;
        s += pa.x * pa.x + pa.y * pa.y + pa.z * pa.z + pa.w * pa.w;
        float s2 = pb.x * pb.x + pb.y * pb.y + pb.z * pb.z + pb.w * pb.w;
        ssl = wave_reduce_add(s + s2);
    }

    unsigned long long mask = 0;
    for (int i = 0; i < STRIP; ++i) {
        int l = t0 + i;
        unsigned char h;
        if (l == 0) {
            h = 1;  // probs=1 -> logits=+inf -> hard=1
        } else {
            const float* rc = base + (size_t)l * D_;
            f4 ca = *(const f4*)(rc + i0);
            f4 cb = *(const f4*)(rc + i1);
            // accumulate exactly like the round-1 kernel (c-group order)
            float dot = 0.f, ssr = 0.f;
            dot += pa.x * ca.x + pa.y * ca.y + pa.z * ca.z + pa.w * ca.w;
            ssr += ca.x * ca.x + ca.y * ca.y + ca.z * ca.z + ca.w * ca.w;
            dot += pb.x * cb.x + pb.y * cb.y + pb.z * cb.z + pb.w * cb.w;
            ssr += cb.x * cb.x + cb.y * cb.y + cb.z * cb.z + cb.w * cb.w;
            dot = wave_reduce_add(dot);
            ssr = wave_reduce_add(ssr);
            float nl = fmaxf(sqrtf(ssl), 1e-12f);
            float nr = fmaxf(sqrtf(ssr), 1e-12f);
            float cosv;
            if (!nonid) {
                cosv = dot / (nl * nr);
            } else {
                // general: cos = (q_w @ n_l) . (k_w @ n_r), recomputed from weights
                float* nL = lds + wid * 2 * D_;
                float* nR = nL + D_;
                nL[i0 + 0] = pa.x / nl; nL[i0 + 1] = pa.y / nl;
                nL[i0 + 2] = pa.z / nl; nL[i0 + 3] = pa.w / nl;
                nL[i1 + 0] = pb.x / nl; nL[i1 + 1] = pb.y / nl;
                nL[i1 + 2] = pb.z / nl; nL[i1 + 3] = pb.w / nl;
                nR[i0 + 0] = ca.x / nr; nR[i0 + 1] = ca.y / nr;
                nR[i0 + 2] = ca.z / nr; nR[i0 + 3] = ca.w / nr;
                nR[i1 + 0] = cb.x / nr; nR[i1 + 1] = cb.y / nr;
                nR[i1 + 2] = cb.z / nr; nR[i1 + 3] = cb.w / nr;
                float acc = 0.f;
                for (int r8 = 0; r8 < 8; ++r8) {
                    int row = lane + 64 * r8;
                    float qi = 0.f, ki = 0.f;
                    for (int j = 0; j < D_; ++j) {
                        qi += q_w[row * D_ + j] * nL[j];
                        ki += k_w[row * D_ + j] * nR[j];
                    }
                    acc += qi * ki;
                }
                cosv = wave_reduce_add(acc);
            }
            float p = fminf(fmaxf(0.5f * (1.0f - cosv), 0.0f), 1.0f);
            float u = noise[b * L_ + l];
            float x = (logf(p) - log1pf(-p)) + (logf(u) - log1pf(-u));
            float s = 1.0f / (1.0f + expf(-x));
            h = (s > 0.5f) ? (unsigned char)1 : (unsigned char)0;
            pa = ca; pb = cb; ssl = ssr;
        }
        mask |= ((unsigned long long)h) << (8 * i);
    }
    if (lane == 0) hard64[wave] = mask;
}

// Per-batch-row inclusive scan of hard flags -> segment start positions + count.
__global__ __launch_bounds__(256) void k_scan(const unsigned char* __restrict__ hard,
                                              int* __restrict__ seg_starts,
                                              int* __restrict__ ksum) {
    int b = blockIdx.x;
    int tid = threadIdx.x;
    const uint4* hb = (const uint4*)(hard + b * L_);
    uint4 v = hb[tid];  // 16 boundary bytes (each 0 or 1)
    int s = __popc(v.x) + __popc(v.y) + __popc(v.z) + __popc(v.w);
    __shared__ int sdata[256];
    sdata[tid] = s;
    __syncthreads();
    for (int off = 1; off < 256; off <<= 1) {
        int t = (tid >= off) ? sdata[tid - off] : 0;
        __syncthreads();
        sdata[tid] += t;
        __syncthreads();
    }
    int run = sdata[tid] - s;
    int base = tid * 16;
    unsigned wds[4] = {v.x, v.y, v.z, v.w};
#pragma unroll
    for (int wi = 0; wi < 4; ++wi)
#pragma unroll
        for (int byte = 0; byte < 4; ++byte)
            if ((wds[wi] >> (8 * byte)) & 1) {
                run++;
                seg_starts[b * L_ + run - 1] = base + wi * 4 + byte;
            }
    if (tid == 255) ksum[b] = sdata[255];
}

// 4 waves/block; wave handles one (segment slot j, batch b). Output pooled[j,b,d].
__global__ __launch_bounds__(256) void k_pool(const float* __restrict__ hidden,
                                              const int* __restrict__ seg_starts,
                                              const int* __restrict__ ksum,
                                              float* __restrict__ out) {
    int wid = threadIdx.x >> 6, lane = threadIdx.x & 63;
    int j = blockIdx.x * 4 + wid, b = blockIdx.y;
    int S = ksum[b];
    int i0 = lane * 4, i1 = i0 + 256;
    f4 a0 = (f4)(0.0f);
    f4 a1 = (f4)(0.0f);
    if (j < S) {
        int start = seg_starts[b * L_ + j];
        int end = (j + 1 < S) ? seg_starts[b * L_ + j + 1] : L_;
        const float* base = hidden + ((size_t)b * L_ + start) * D_;
        for (int t = start; t < end; ++t, base += D_) {
            f4 v0 = *(const f4*)(base + i0);
            f4 v1 = *(const f4*)(base + i1);
            a0 += v0;
            a1 += v1;
        }
        float inv = 1.0f / (float)(end - start);
        // divide (not multiply) to match reference sums/counts rounding as closely
        // as possible? reference does sums / cnts -> use division per component.
        a0.x /= (float)(end - start); a0.y /= (float)(end - start);
        a0.z /= (float)(end - start); a0.w /= (float)(end - start);
        a1.x /= (float)(end - start); a1.y /= (float)(end - start);
        a1.z /= (float)(end - start); a1.w /= (float)(end - start);
        (void)inv;
    }
    float* o = out + ((size_t)j * B_ + b) * D_;
    __builtin_nontemporal_store(a0, (f4*)(o + i0));
    __builtin_nontemporal_store(a1, (f4*)(o + i1));
}

__global__ void k_loss(const int* __restrict__ ksum, float* __restrict__ out_loss) {
    __shared__ double sh[17];
    int tid = threadIdx.x;
    double n = (double)L_;
    if (tid < 8) sh[tid] = lgamma((double)ksum[tid] + 1.0);
    else if (tid < 16) sh[tid] = lgamma(n - (double)ksum[tid - 8] + 1.0);
    else if (tid == 16) sh[16] = lgamma(n + 1.0);
    __syncthreads();
    if (tid == 0) {
        double acc = 0.0, lg = sh[16];
        for (int b = 0; b < 8; ++b) {
            double k = (double)ksum[b];
            acc += lg - sh[b] - sh[8 + b] + k * log(0.2) + (n - k) * log(0.8);
        }
        out_loss[0] = (float)(-(acc / 8.0) / n);
    }
}

extern "C" void kernel_launch(void* const* d_in, const int* in_sizes, int n_in,
                              void* d_out, int out_size, void* d_ws, size_t ws_size,
                              hipStream_t stream) {
    const float* hidden = (const float*)d_in[0];
    const float* q_w = (const float*)d_in[1];
    const float* k_w = (const float*)d_in[2];
    const float* noise = (const float*)d_in[3];
    float* out = (float*)d_out;

    char* ws = (char*)d_ws;
    int* nonid_arr = (int*)(ws + 0);
    int* ksum = (int*)(ws + 512);
    unsigned char* hard = (unsigned char*)(ws + 1024);
    unsigned long long* hard64 = (unsigned long long*)(ws + 1024);
    int* seg_starts = (int*)(ws + 34816);

    k_check<<<64, 256, 0, stream>>>(q_w, k_w, nonid_arr);
    k_boundary<<<(B_ * L_ / STRIP) / 4, 256, 0, stream>>>(hidden, noise, q_w, k_w,
                                                          nonid_arr, hard64);
    k_scan<<<B_, 256, 0, stream>>>(hard, seg_starts, ksum);
    k_pool<<<dim3(L_ / 4, B_), 256, 0, stream>>>(hidden, seg_starts, ksum, out);
    k_loss<<<1, 64, 0, stream>>>(ksum, out + (size_t)L_ * B_ * D_);
}